// Round 20
// baseline (204.926 us; speedup 1.0000x reference)
//
#include <hip/hip_runtime.h>
#include <hip/hip_bf16.h>

#define Bdim 32
#define Ndim 4096
#define Cdim 768
#define Kdim 64

typedef float f32x4 __attribute__((ext_vector_type(4)));
typedef short s16x4 __attribute__((ext_vector_type(4)));
typedef short s16x8 __attribute__((ext_vector_type(8)));
typedef __bf16 bf16x8 __attribute__((ext_vector_type(8)));

__device__ __forceinline__ short f2bf(float f) {
  return __builtin_bit_cast(short, (__bf16)f);   // hw RNE cvt
}
__device__ __forceinline__ float bf2f(short s) {
  return (float)__builtin_bit_cast(__bf16, s);
}
__device__ __forceinline__ f32x4 MFMA(s16x8 a, s16x8 b, f32x4 c) {
  return __builtin_amdgcn_mfma_f32_16x16x32_bf16(
      __builtin_bit_cast(bf16x8, a), __builtin_bit_cast(bf16x8, b), c, 0, 0, 0);
}

// ---------------- k0_init: W cvt (fragment order) + zero out + zero sums ----------
__global__ __launch_bounds__(256) void k0_init(
    const float* __restrict__ W, short* __restrict__ Wr,
    float* __restrict__ sum, float* __restrict__ out) {
  const int idx = blockIdx.x * 256 + threadIdx.x;  // 0..98303 (384 blocks)
  f32x4 z = {0.f, 0.f, 0.f, 0.f};
  f32x4* o4 = (f32x4*)out;
#pragma unroll
  for (int j = 0; j < 4; ++j) o4[idx + j * 98304] = z;
  if (idx < Bdim * Kdim) sum[idx] = 0.f;
  if (idx < Kdim * Cdim / 8) {
    int k = idx / (Cdim / 8), c8 = idx % (Cdim / 8);
    int cs = c8 >> 2, g = c8 & 3;
    int t = k >> 4, i = k & 15;
    const float* src = W + (size_t)k * Cdim + c8 * 8;
    s16x8 v;
#pragma unroll
    for (int e = 0; e < 8; ++e) v[e] = f2bf(src[e]);
    *(s16x8*)(Wr + ((((size_t)cs * 4 + t) * 4 + g) * 16 + i) * 8) = v;
  }
}

// ---------------- k1: P = bf16(exp(x @ W^T)) (exotic layout) + atomic sums --------
// R12-proven core. NEW: P-store packed -- per t, the four r-values are
// consecutive shorts in one 8-block (n&7 = g*4+r, same n>>3), so 4x 2B
// scattered stores become ONE 8B s16x4 store (16 stores/thread -> 4).
__global__ __launch_bounds__(256) void k1_logits(
    const float* __restrict__ x, const short* __restrict__ Wr,
    short* __restrict__ P, float* __restrict__ sum) {
  const int blk = blockIdx.x;
  const int b = blk >> 6;          // 64 ntiles per batch
  const int ntile = blk & 63;      // 64 rows per tile
  const int tid = threadIdx.x;
  const int w = tid >> 6;
  const int l = tid & 63;
  const int g = l >> 4, i = l & 15;

  const float* xrow = x + (size_t)(b * Ndim + ntile * 64 + w * 16 + i) * Cdim;
  f32x4 acc[4] = {};

  for (int grp = 0; grp < 6; ++grp) {   // 6 groups x (4 cs-steps of K=32)
    const int cbase = grp * 128 + g * 8;
    f32x4 xv[8];
    s16x8 wv[4][4];
#pragma unroll
    for (int s = 0; s < 4; ++s) {
      const f32x4* ap = (const f32x4*)(xrow + cbase + s * 32);
      xv[2 * s] = ap[0];
      xv[2 * s + 1] = ap[1];
    }
#pragma unroll
    for (int s = 0; s < 4; ++s) {
#pragma unroll
      for (int t = 0; t < 4; ++t) {
        wv[s][t] = *(const s16x8*)(
            Wr + ((((size_t)(grp * 4 + s) * 4 + t) * 4 + g) * 16 + i) * 8);
      }
    }
#pragma unroll
    for (int s = 0; s < 4; ++s) {
      s16x8 af;
#pragma unroll
      for (int e = 0; e < 4; ++e) af[e] = f2bf(xv[2 * s][e]);
#pragma unroll
      for (int e = 0; e < 4; ++e) af[4 + e] = f2bf(xv[2 * s + 1][e]);
#pragma unroll
      for (int t = 0; t < 4; ++t) acc[t] = MFMA(af, wv[s][t], acc[t]);
    }
  }

  // epilogue: P = bf16(exp(logit)); packed 8B store per t; atomic tile sums
  short* Pb = P + (size_t)b * (Ndim * Kdim);
  const int n0 = ntile * 64 + w * 16 + g * 4;  // base n for r=0..3 (one 8-block)
  float sv[4];
#pragma unroll
  for (int t = 0; t < 4; ++t) {
    const int k = t * 16 + i;                  // D col = l&15
    s16x4 pk;
    sv[t] = 0.f;
#pragma unroll
    for (int r = 0; r < 4; ++r) {              // D row = 4*(l>>4)+reg
      short hv = f2bf(__expf(acc[t][r]));
      pk[r] = hv;
      sv[t] += bf2f(hv);                       // sum the ROUNDED values
    }
    *(s16x4*)(Pb + (size_t)(n0 >> 3) * 512 + k * 8 + (n0 & 7)) = pk;
    sv[t] += __shfl_xor(sv[t], 16);
    sv[t] += __shfl_xor(sv[t], 32);
  }
  __shared__ float rs[4][4][16];  // [w][t][i]
  if (g == 0) {
#pragma unroll
    for (int t = 0; t < 4; ++t) rs[w][t][i] = sv[t];
  }
  __syncthreads();
  if (w == 0 && g == 0) {
#pragma unroll
    for (int t = 0; t < 4; ++t) {
      float S = rs[0][t][i] + rs[1][t][i] + rs[2][t][i] + rs[3][t][i];
      unsafeAtomicAdd(&sum[b * 64 + t * 16 + i], S);
    }
  }
}

// ---------------- k3: out[b,k,c] += (1/sum[k]) * sum_{n in q} P[n,k]*x[b,n,c] ------
// R18-proven core (dbuf LDS, one soft barrier/chunk, atomic out-epilogue).
#define CT 48    // c-columns per block
#define NCH 128  // n rows staged per chunk
#define NQ 4     // n-splits
#define BUFO (CT * 128)  // shorts per LDS buffer
__device__ __forceinline__ int swz(int c) {
  return ((((c >> 3) ^ c) & 7) << 4);  // byte-XOR within a 256B row
}
__global__ __launch_bounds__(256) void k3_tokens(
    const float* __restrict__ x, const short* __restrict__ P,
    const float* __restrict__ sum, float* __restrict__ out) {
  __shared__ short xs[2 * BUFO];  // 2 x (CT rows x 256 bytes)
  char* xsb = (char*)xs;
  const int blk = blockIdx.x;
  const int q = blk & 3;
  const int ct = (blk >> 2) & 15;
  const int b = blk >> 6;
  const int tid = threadIdx.x;
  const int w = tid >> 6, l = tid & 63, g = l >> 4, i = l & 15;

  const float* xb = x + (size_t)b * Ndim * Cdim;
  const short* Pb = P + (size_t)b * (Ndim * Kdim);

  // inv-denoms for this lane's 4 output rows (L2-hot loads + IEEE div)
  float iv4[4];
#pragma unroll
  for (int r = 0; r < 4; ++r) iv4[r] = 1.f / sum[b * 64 + w * 16 + g * 4 + r];

  f32x4 acc[3] = {};

#define LOADX(ch, buf)                                                        \
  do {                                                                        \
    const int n0_ = (ch) * NCH;                                               \
    _Pragma("unroll") for (int uu = 0; uu < 3; ++uu) {                        \
      int u_ = tid + uu * 256;                                                \
      int n_ = u_ / 6, c8_ = u_ % 6;                                          \
      const f32x4* src_ =                                                     \
          (const f32x4*)(xb + (size_t)(n0_ + n_) * Cdim + ct * CT + c8_ * 8); \
      buf[uu][0] = src_[0];                                                   \
      buf[uu][1] = src_[1];                                                   \
    }                                                                         \
  } while (0)

#define LOADL(ch, lvb)                                                        \
  do {                                                                        \
    const int nb8_ = (ch) * 16;                                               \
    _Pragma("unroll") for (int ns = 0; ns < 4; ++ns) {                        \
      lvb[ns] = *(const s16x8*)(Pb + (size_t)(nb8_ + ns * 4 + g) * 512 +      \
                                (w * 16 + i) * 8);                            \
    }                                                                         \
  } while (0)

#define STORELDS(base, buf)                                                   \
  do {                                                                        \
    _Pragma("unroll") for (int uu = 0; uu < 3; ++uu) {                        \
      int u_ = tid + uu * 256;                                                \
      int n_ = u_ / 6, c8_ = u_ % 6;                                          \
      _Pragma("unroll") for (int e = 0; e < 8; ++e) {                         \
        int c_ = c8_ * 8 + e;                                                 \
        float fv_ = (e < 4) ? buf[uu][0][e] : buf[uu][1][e - 4];              \
        *(short*)(xsb + (base) + c_ * 256 + ((2 * n_) ^ swz(c_))) = f2bf(fv_);\
      }                                                                       \
    }                                                                         \
  } while (0)

#define COMPUTE(base, lvb)                                                    \
  do {                                                                        \
    _Pragma("unroll") for (int ns = 0; ns < 4; ++ns) {                        \
      _Pragma("unroll") for (int cs = 0; cs < 3; ++cs) {                      \
        const int c_ = cs * 16 + i;                                           \
        s16x8 bfr_ = *(const s16x8*)(xsb + (base) + c_ * 256 +                \
                                     ((ns * 64 + g * 16) ^ swz(c_)));         \
        acc[cs] = MFMA(lvb[ns], bfr_, acc[cs]);                               \
      }                                                                       \
    }                                                                         \
  } while (0)

#define SOFT_BARRIER()                                                        \
  do {                                                                        \
    asm volatile("s_waitcnt lgkmcnt(0)" ::: "memory");                        \
    __builtin_amdgcn_s_barrier();                                             \
    __builtin_amdgcn_sched_barrier(0);                                        \
  } while (0)

  f32x4 stA[3][2], stB[3][2];
  s16x8 lvA[4], lvB[4];

  const int ch0 = q * 8;  // 8 chunks of 128 n per block
  LOADX(ch0, stA);
  LOADL(ch0, lvA);
  LOADX(ch0 + 1, stB);
  LOADL(ch0 + 1, lvB);
  STORELDS(0, stA);
  SOFT_BARRIER();

  for (int c = 0; c < 8; c += 2) {
    if (c + 2 < 8) LOADX(ch0 + c + 2, stA);
    STORELDS(BUFO * 2, stB);
    COMPUTE(0, lvA);
    if (c + 2 < 8) LOADL(ch0 + c + 2, lvA);
    SOFT_BARRIER();
    if (c + 3 < 8) LOADX(ch0 + c + 3, stB);
    if (c + 2 < 8) STORELDS(0, stA);
    COMPUTE(BUFO * 2, lvB);
    if (c + 3 < 8) LOADL(ch0 + c + 3, lvB);
    SOFT_BARRIER();
  }

  // epilogue: scaled atomic accumulate into out (zeroed by k0_init)
  float* ob = out + (size_t)b * (Kdim * Cdim);
#pragma unroll
  for (int r = 0; r < 4; ++r) {
    const int k = w * 16 + g * 4 + r;
#pragma unroll
    for (int cs = 0; cs < 3; ++cs) {
      unsafeAtomicAdd(&ob[(size_t)k * Cdim + ct * CT + cs * 16 + i],
                      acc[cs][r] * iv4[r]);
    }
  }
#undef LOADX
#undef LOADL
#undef STORELDS
#undef COMPUTE
#undef SOFT_BARRIER
}

extern "C" void kernel_launch(void* const* d_in, const int* in_sizes, int n_in,
                              void* d_out, int out_size, void* d_ws, size_t ws_size,
                              hipStream_t stream) {
  const float* x = (const float*)d_in[0];
  const float* W = (const float*)d_in[1];
  float* out = (float*)d_out;
  char* ws = (char*)d_ws;

  short* Wb = (short*)ws;                                   // 96 KB (pad 128K)
  short* P = (short*)(ws + (1 << 17));                      // 16 MB bf16 exp-logits
  float* sum = (float*)(ws + (1 << 17) + (size_t)Bdim * Ndim * Kdim * 2);  // 2048

  hipLaunchKernelGGL(k0_init, dim3(384), dim3(256), 0, stream, W, Wb, sum, out);
  hipLaunchKernelGGL(k1_logits, dim3(Bdim * 64), dim3(256), 0, stream, x, Wb, P, sum);
  hipLaunchKernelGGL(k3_tokens, dim3(Bdim * 16 * NQ), dim3(256), 0, stream,
                     x, P, sum, out);
}

// Round 21
// 201.064 us; speedup vs baseline: 1.0192x; 1.0192x over previous
//
#include <hip/hip_runtime.h>
#include <hip/hip_bf16.h>

#define Bdim 32
#define Ndim 4096
#define Cdim 768
#define Kdim 64

typedef float f32x4 __attribute__((ext_vector_type(4)));
typedef short s16x8 __attribute__((ext_vector_type(8)));
typedef __bf16 bf16x8 __attribute__((ext_vector_type(8)));

__device__ __forceinline__ short f2bf(float f) {
  return __builtin_bit_cast(short, (__bf16)f);   // hw RNE cvt
}
__device__ __forceinline__ float bf2f(short s) {
  return (float)__builtin_bit_cast(__bf16, s);
}
__device__ __forceinline__ f32x4 MFMA(s16x8 a, s16x8 b, f32x4 c) {
  return __builtin_amdgcn_mfma_f32_16x16x32_bf16(
      __builtin_bit_cast(bf16x8, a), __builtin_bit_cast(bf16x8, b), c, 0, 0, 0);
}

// ---------------- k0_init: W cvt (fragment order) + zero out + zero sums ----------
__global__ __launch_bounds__(256) void k0_init(
    const float* __restrict__ W, short* __restrict__ Wr,
    float* __restrict__ sum, float* __restrict__ out) {
  const int idx = blockIdx.x * 256 + threadIdx.x;  // 0..98303 (384 blocks)
  f32x4 z = {0.f, 0.f, 0.f, 0.f};
  f32x4* o4 = (f32x4*)out;
#pragma unroll
  for (int j = 0; j < 4; ++j) o4[idx + j * 98304] = z;
  if (idx < Bdim * Kdim) sum[idx] = 0.f;
  if (idx < Kdim * Cdim / 8) {
    int k = idx / (Cdim / 8), c8 = idx % (Cdim / 8);
    int cs = c8 >> 2, g = c8 & 3;
    int t = k >> 4, i = k & 15;
    const float* src = W + (size_t)k * Cdim + c8 * 8;
    s16x8 v;
#pragma unroll
    for (int e = 0; e < 8; ++e) v[e] = f2bf(src[e]);
    *(s16x8*)(Wr + ((((size_t)cs * 4 + t) * 4 + g) * 16 + i) * 8) = v;
  }
}

// ---------------- k1: P = bf16(exp(x @ W^T)) (exotic layout) + atomic sums --------
// R12-proven core. Epilogue unsafeAtomicAdds tile sums into sum[b*64+k].
__global__ __launch_bounds__(256) void k1_logits(
    const float* __restrict__ x, const short* __restrict__ Wr,
    short* __restrict__ P, float* __restrict__ sum) {
  const int blk = blockIdx.x;
  const int b = blk >> 6;          // 64 ntiles per batch
  const int ntile = blk & 63;      // 64 rows per tile
  const int tid = threadIdx.x;
  const int w = tid >> 6;
  const int l = tid & 63;
  const int g = l >> 4, i = l & 15;

  const float* xrow = x + (size_t)(b * Ndim + ntile * 64 + w * 16 + i) * Cdim;
  f32x4 acc[4] = {};

  for (int grp = 0; grp < 6; ++grp) {   // 6 groups x (4 cs-steps of K=32)
    const int cbase = grp * 128 + g * 8;
    f32x4 xv[8];
    s16x8 wv[4][4];
#pragma unroll
    for (int s = 0; s < 4; ++s) {
      const f32x4* ap = (const f32x4*)(xrow + cbase + s * 32);
      xv[2 * s] = ap[0];
      xv[2 * s + 1] = ap[1];
    }
#pragma unroll
    for (int s = 0; s < 4; ++s) {
#pragma unroll
      for (int t = 0; t < 4; ++t) {
        wv[s][t] = *(const s16x8*)(
            Wr + ((((size_t)(grp * 4 + s) * 4 + t) * 4 + g) * 16 + i) * 8);
      }
    }
#pragma unroll
    for (int s = 0; s < 4; ++s) {
      s16x8 af;
#pragma unroll
      for (int e = 0; e < 4; ++e) af[e] = f2bf(xv[2 * s][e]);
#pragma unroll
      for (int e = 0; e < 4; ++e) af[4 + e] = f2bf(xv[2 * s + 1][e]);
#pragma unroll
      for (int t = 0; t < 4; ++t) acc[t] = MFMA(af, wv[s][t], acc[t]);
    }
  }

  // epilogue: P = bf16(exp(logit)), store + per-tile sum -> atomic accumulate
  short* Pb = P + (size_t)b * (Ndim * Kdim);
  float sv[4];
#pragma unroll
  for (int t = 0; t < 4; ++t) {
    sv[t] = 0.f;
#pragma unroll
    for (int r = 0; r < 4; ++r) {
      int n = ntile * 64 + w * 16 + g * 4 + r;  // D row = 4*(l>>4)+reg
      int k = t * 16 + i;                       // D col = l&15
      short hv = f2bf(__expf(acc[t][r]));
      Pb[(n >> 3) * 512 + k * 8 + (n & 7)] = hv;
      sv[t] += bf2f(hv);                        // sum the ROUNDED values
    }
    sv[t] += __shfl_xor(sv[t], 16);
    sv[t] += __shfl_xor(sv[t], 32);
  }
  __shared__ float rs[4][4][16];  // [w][t][i]
  if (g == 0) {
#pragma unroll
    for (int t = 0; t < 4; ++t) rs[w][t][i] = sv[t];
  }
  __syncthreads();
  if (w == 0 && g == 0) {
#pragma unroll
    for (int t = 0; t < 4; ++t) {
      float S = rs[0][t][i] + rs[1][t][i] + rs[2][t][i] + rs[3][t][i];
      unsafeAtomicAdd(&sum[b * 64 + t * 16 + i], S);
    }
  }
}

// ---------------- k3: out[b,k,c] += (1/sum[k]) * sum_{n in q} P[n,k]*x[b,n,c] ------
// R18-proven core (dbuf LDS, one soft barrier/chunk, atomic out-epilogue).
#define CT 48    // c-columns per block
#define NCH 128  // n rows staged per chunk
#define NQ 4     // n-splits
#define BUFO (CT * 128)  // shorts per LDS buffer
__device__ __forceinline__ int swz(int c) {
  return ((((c >> 3) ^ c) & 7) << 4);  // byte-XOR within a 256B row
}
__global__ __launch_bounds__(256) void k3_tokens(
    const float* __restrict__ x, const short* __restrict__ P,
    const float* __restrict__ sum, float* __restrict__ out) {
  __shared__ short xs[2 * BUFO];  // 2 x (CT rows x 256 bytes)
  char* xsb = (char*)xs;
  const int blk = blockIdx.x;
  const int q = blk & 3;
  const int ct = (blk >> 2) & 15;
  const int b = blk >> 6;
  const int tid = threadIdx.x;
  const int w = tid >> 6, l = tid & 63, g = l >> 4, i = l & 15;

  const float* xb = x + (size_t)b * Ndim * Cdim;
  const short* Pb = P + (size_t)b * (Ndim * Kdim);

  // inv-denoms for this lane's 4 output rows (L2-hot loads + IEEE div)
  float iv4[4];
#pragma unroll
  for (int r = 0; r < 4; ++r) iv4[r] = 1.f / sum[b * 64 + w * 16 + g * 4 + r];

  f32x4 acc[3] = {};

#define LOADX(ch, buf)                                                        \
  do {                                                                        \
    const int n0_ = (ch) * NCH;                                               \
    _Pragma("unroll") for (int uu = 0; uu < 3; ++uu) {                        \
      int u_ = tid + uu * 256;                                                \
      int n_ = u_ / 6, c8_ = u_ % 6;                                          \
      const f32x4* src_ =                                                     \
          (const f32x4*)(xb + (size_t)(n0_ + n_) * Cdim + ct * CT + c8_ * 8); \
      buf[uu][0] = src_[0];                                                   \
      buf[uu][1] = src_[1];                                                   \
    }                                                                         \
  } while (0)

#define LOADL(ch, lvb)                                                        \
  do {                                                                        \
    const int nb8_ = (ch) * 16;                                               \
    _Pragma("unroll") for (int ns = 0; ns < 4; ++ns) {                        \
      lvb[ns] = *(const s16x8*)(Pb + (size_t)(nb8_ + ns * 4 + g) * 512 +      \
                                (w * 16 + i) * 8);                            \
    }                                                                         \
  } while (0)

#define STORELDS(base, buf)                                                   \
  do {                                                                        \
    _Pragma("unroll") for (int uu = 0; uu < 3; ++uu) {                        \
      int u_ = tid + uu * 256;                                                \
      int n_ = u_ / 6, c8_ = u_ % 6;                                          \
      _Pragma("unroll") for (int e = 0; e < 8; ++e) {                         \
        int c_ = c8_ * 8 + e;                                                 \
        float fv_ = (e < 4) ? buf[uu][0][e] : buf[uu][1][e - 4];              \
        *(short*)(xsb + (base) + c_ * 256 + ((2 * n_) ^ swz(c_))) = f2bf(fv_);\
      }                                                                        \
    }                                                                         \
  } while (0)

#define COMPUTE(base, lvb)                                                    \
  do {                                                                        \
    _Pragma("unroll") for (int ns = 0; ns < 4; ++ns) {                        \
      _Pragma("unroll") for (int cs = 0; cs < 3; ++cs) {                      \
        const int c_ = cs * 16 + i;                                           \
        s16x8 bfr_ = *(const s16x8*)(xsb + (base) + c_ * 256 +                \
                                     ((ns * 64 + g * 16) ^ swz(c_)));         \
        acc[cs] = MFMA(lvb[ns], bfr_, acc[cs]);                               \
      }                                                                       \
    }                                                                         \
  } while (0)

#define SOFT_BARRIER()                                                        \
  do {                                                                        \
    asm volatile("s_waitcnt lgkmcnt(0)" ::: "memory");                        \
    __builtin_amdgcn_s_barrier();                                             \
    __builtin_amdgcn_sched_barrier(0);                                        \
  } while (0)

  f32x4 stA[3][2], stB[3][2];
  s16x8 lvA[4], lvB[4];

  const int ch0 = q * 8;  // 8 chunks of 128 n per block
  LOADX(ch0, stA);
  LOADL(ch0, lvA);
  LOADX(ch0 + 1, stB);
  LOADL(ch0 + 1, lvB);
  STORELDS(0, stA);
  SOFT_BARRIER();

  for (int c = 0; c < 8; c += 2) {
    if (c + 2 < 8) LOADX(ch0 + c + 2, stA);
    STORELDS(BUFO * 2, stB);
    COMPUTE(0, lvA);
    if (c + 2 < 8) LOADL(ch0 + c + 2, lvA);
    SOFT_BARRIER();
    if (c + 3 < 8) LOADX(ch0 + c + 3, stB);
    if (c + 2 < 8) STORELDS(0, stA);
    COMPUTE(BUFO * 2, lvB);
    if (c + 3 < 8) LOADL(ch0 + c + 3, lvB);
    SOFT_BARRIER();
  }

  // epilogue: scaled atomic accumulate into out (zeroed by k0_init)
  float* ob = out + (size_t)b * (Kdim * Cdim);
#pragma unroll
  for (int r = 0; r < 4; ++r) {
    const int k = w * 16 + g * 4 + r;
#pragma unroll
    for (int cs = 0; cs < 3; ++cs) {
      unsafeAtomicAdd(&ob[(size_t)k * Cdim + ct * CT + cs * 16 + i],
                      acc[cs][r] * iv4[r]);
    }
  }
#undef LOADX
#undef LOADL
#undef STORELDS
#undef COMPUTE
#undef SOFT_BARRIER
}

extern "C" void kernel_launch(void* const* d_in, const int* in_sizes, int n_in,
                              void* d_out, int out_size, void* d_ws, size_t ws_size,
                              hipStream_t stream) {
  const float* x = (const float*)d_in[0];
  const float* W = (const float*)d_in[1];
  float* out = (float*)d_out;
  char* ws = (char*)d_ws;

  short* Wb = (short*)ws;                                   // 96 KB (pad 128K)
  short* P = (short*)(ws + (1 << 17));                      // 16 MB bf16 exp-logits
  float* sum = (float*)(ws + (1 << 17) + (size_t)Bdim * Ndim * Kdim * 2);  // 2048

  hipLaunchKernelGGL(k0_init, dim3(384), dim3(256), 0, stream, W, Wb, sum, out);
  hipLaunchKernelGGL(k1_logits, dim3(Bdim * 64), dim3(256), 0, stream, x, Wb, P, sum);
  hipLaunchKernelGGL(k3_tokens, dim3(Bdim * 16 * NQ), dim3(256), 0, stream,
                     x, P, sum, out);
}